// Round 2
// baseline (302.828 us; speedup 1.0000x reference)
//
#include <hip/hip_runtime.h>
#include <math.h>

// Problem geometry (fixed by the reference):
//   fft_coeffs: (32, 6, 384, 384) fp32; kernel: (3,1,21,21) fp32 uniform box.
//   out ch 0-2: log1p(mag) - boxfilter21x21(log1p(mag)) * w_c  (zero-padded)
//   out ch 3-5: copy of input ch 3-5.
#define HH    384
#define WW    384
#define TILE   64
#define HALO   10
#define KW     21
#define LDIM   84          // TILE + 2*HALO
#define PLANE 147456       // 384*384

__global__ __launch_bounds__(256)
void spectral_residual_fused_kernel(const float* __restrict__ in,
                                    const float* __restrict__ kern,
                                    float* __restrict__ out)
{
    // 84x84 log1p tile + 84x64 horizontal sums: 49.7 KB LDS -> 3 blocks/CU
    __shared__ float lm[LDIM * LDIM];
    __shared__ float hs[LDIM * TILE];

    const int tid   = threadIdx.x;
    const int tx    = blockIdx.x;          // tile col 0..5
    const int ty    = blockIdx.y;          // tile row 0..5
    const int plane = blockIdx.z;          // n*6 + c, c in 0..5
    const int n     = plane / 6;
    const int c     = plane - n * 6;

    const size_t plane_off = (size_t)plane * PLANE;

    if (c >= 3) {
        // ---- Phase channels: pure copy. Each of the 36 blocks per plane
        // copies a contiguous 16 KB chunk as float4 (fully coalesced). ----
        const float4* __restrict__ s = (const float4*)(in + plane_off);
        float4*       __restrict__ d = (float4*)(out + plane_off);
        const int chunk = ty * 6 + tx;          // 0..35
        const int base  = chunk * 1024;         // float4 units; 1024*36*4 = PLANE
        #pragma unroll
        for (int i = 0; i < 4; ++i) {
            int e = base + i * 256 + tid;
            d[e] = s[e];
        }
        return;
    }

    // Depthwise kernel is uniform (ones/441): one weight per channel.
    const float w = kern[c * (KW * KW)];

    const float* __restrict__ src = in  + plane_off;
    float*       __restrict__ dst = out + plane_off;

    const int gy0 = ty * TILE - HALO;
    const int gx0 = tx * TILE - HALO;

    // ---- Stage log1p(mag) halo tile into LDS (zero-pad OOB = conv padding) ----
    for (int idx = tid; idx < LDIM * LDIM; idx += 256) {
        int r   = idx / LDIM;
        int col = idx - r * LDIM;
        int gy  = gy0 + r;
        int gx  = gx0 + col;
        float v = 0.0f;
        if (gy >= 0 && gy < HH && gx >= 0 && gx < WW)
            v = log1pf(src[gy * WW + gx]);
        lm[idx] = v;
    }
    __syncthreads();

    // ---- Horizontal 21-tap sums: hs[r][x] = sum_k lm[r][x+k] ----
    // Consecutive lanes hit consecutive LDS addrs (2-way aliasing only, free).
    for (int e = tid; e < LDIM * TILE; e += 256) {
        int r = e >> 6;            // 0..83
        int x = e & (TILE - 1);    // 0..63
        const float* row = &lm[r * LDIM + x];
        float s = 0.0f;
        #pragma unroll
        for (int k = 0; k < KW; ++k) s += row[k];
        hs[e] = s;
    }
    __syncthreads();

    // ---- Vertical 21-tap + scale + residual write ----
    for (int p = tid; p < TILE * TILE; p += 256) {
        int y = p >> 6;
        int x = p & (TILE - 1);
        float s = 0.0f;
        #pragma unroll
        for (int k = 0; k < KW; ++k) s += hs[(y + k) * TILE + x];
        float env    = w * s;
        float center = lm[(y + HALO) * LDIM + (x + HALO)];
        dst[(ty * TILE + y) * WW + (tx * TILE + x)] = center - env;
    }
}

extern "C" void kernel_launch(void* const* d_in, const int* in_sizes, int n_in,
                              void* d_out, int out_size, void* d_ws, size_t ws_size,
                              hipStream_t stream)
{
    const float* in   = (const float*)d_in[0];
    const float* kern = (const float*)d_in[1];
    float*       out  = (float*)d_out;

    // One fused launch: 6x6 tiles per plane, 32 batches x 6 channels.
    dim3 grid(WW / TILE, HH / TILE, 32 * 6);
    spectral_residual_fused_kernel<<<grid, 256, 0, stream>>>(in, kern, out);
}

// Round 3
// 257.912 us; speedup vs baseline: 1.1742x; 1.1742x over previous
//
#include <hip/hip_runtime.h>
#include <math.h>

// fft_coeffs: (32, 6, 384, 384) fp32; kernel: (3,1,21,21) fp32 uniform box.
//   out ch 0-2: log1p(mag) - boxfilter21x21(log1p(mag)) * w_c  (zero-padded)
//   out ch 3-5: copy.
// Strategy: separable box filter with per-thread sliding-window running sums.
#define HH    384
#define WW    384
#define TILE   64
#define HALO   10
#define KW     21
#define LDIM   84          // TILE + 2*HALO
#define LMS    85          // lm row stride (pad: 85 odd-ish -> conflict-free)
#define HSS    65          // hs row stride (pad 64+1)
#define PLANE 147456       // 384*384

__global__ __launch_bounds__(256)
void spectral_residual_fused_kernel(const float* __restrict__ in,
                                    const float* __restrict__ kern,
                                    float* __restrict__ out)
{
    __shared__ float lm[LDIM * LMS];   // 84x85 log-magnitude halo tile (28.6 KB)
    __shared__ float hs[LDIM * HSS];   // 84x65 horizontal 21-sums     (21.8 KB)

    const int tid   = threadIdx.x;
    const int tx    = blockIdx.x;          // tile col 0..5
    const int ty    = blockIdx.y;          // tile row 0..5
    const int plane = blockIdx.z;          // n*6 + c
    const int c     = plane % 6;

    const size_t plane_off = (size_t)plane * PLANE;

    if (c >= 3) {
        // Phase channels: contiguous 16 KB float4 copy per block (coalesced).
        const float4* __restrict__ s = (const float4*)(in + plane_off);
        float4*       __restrict__ d = (float4*)(out + plane_off);
        const int base = (ty * 6 + tx) * 1024;      // float4 units
        #pragma unroll
        for (int i = 0; i < 4; ++i) {
            int e = base + i * 256 + tid;
            d[e] = s[e];
        }
        return;
    }

    const float w = kern[c * (KW * KW)];   // uniform depthwise weight (1/441)

    const float* __restrict__ src = in  + plane_off;
    float*       __restrict__ dst = out + plane_off;

    const int gy0 = ty * TILE - HALO;
    const int gx0 = tx * TILE - HALO;

    // ---- Stage log(1+mag) halo tile (zero-pad OOB = conv zero padding) ----
    // x in [0,1] => 1+x in [1,2]: direct log is exact enough (abs err ~1e-7).
    for (int idx = tid; idx < LDIM * LDIM; idx += 256) {
        int r   = idx / LDIM;
        int col = idx - r * LDIM;
        int gy  = gy0 + r;
        int gx  = gx0 + col;
        float v = 0.0f;
        if (gy >= 0 && gy < HH && gx >= 0 && gx < WW)
            v = __logf(1.0f + src[gy * WW + gx]);
        lm[r * LMS + col] = v;
    }
    __syncthreads();

    // ---- Horizontal sliding 21-sum: hs[r][x] = sum_k lm[r][x+k] ----
    // Thread t: row r=t>>1 (0..83), half h=t&1 -> 32 outputs via running sum.
    // Banks: lm addr = 85r+..., 21r mod 32 is a permutation -> 2-way max (free).
    if (tid < 2 * LDIM) {
        const int r  = tid >> 1;
        const int x0 = (tid & 1) * 32;
        const float* row  = &lm[r * LMS + x0];
        float*       hrow = &hs[r * HSS + x0];
        float s = 0.0f;
        #pragma unroll
        for (int k = 0; k < KW; ++k) s += row[k];
        hrow[0] = s;
        #pragma unroll
        for (int i = 1; i < 32; ++i) {
            s += row[i + 20] - row[i - 1];
            hrow[i] = s;
        }
    }
    __syncthreads();

    // ---- Vertical sliding 21-sum + residual, direct coalesced global write ----
    // Wave 0: x=0..63, y0=0; wave 1: x=0..63, y0=32 -> each store is 64
    // consecutive floats of one output row (fully coalesced).
    if (tid < 128) {
        const int x  = tid & 63;
        const int y0 = (tid >> 6) * 32;
        float s = 0.0f;
        #pragma unroll
        for (int k = 0; k < KW; ++k) s += hs[(y0 + k) * HSS + x];
        float* dcol = dst + (ty * TILE + y0) * WW + tx * TILE + x;
        float center = lm[(y0 + HALO) * LMS + (x + HALO)];
        dcol[0] = fmaf(-w, s, center);
        #pragma unroll
        for (int i = 1; i < 32; ++i) {
            s += hs[(y0 + 20 + i) * HSS + x] - hs[(y0 + i - 1) * HSS + x];
            center = lm[(y0 + i + HALO) * LMS + (x + HALO)];
            dcol[i * WW] = fmaf(-w, s, center);
        }
    }
}

extern "C" void kernel_launch(void* const* d_in, const int* in_sizes, int n_in,
                              void* d_out, int out_size, void* d_ws, size_t ws_size,
                              hipStream_t stream)
{
    const float* in   = (const float*)d_in[0];
    const float* kern = (const float*)d_in[1];
    float*       out  = (float*)d_out;

    dim3 grid(WW / TILE, HH / TILE, 32 * 6);
    spectral_residual_fused_kernel<<<grid, 256, 0, stream>>>(in, kern, out);
}